// Round 1
// baseline (133.121 us; speedup 1.0000x reference)
//
#include <hip/hip_runtime.h>

#define BB 4
#define NN 16384
#define SS 2048
#define CC 64
#define NS 32
#define KK 33   // NS + 1 (fps_idx prepended)
#define OC 70   // 3 raw xyz + 3 centered xyz + 64 features

// --- prevent fma contraction so d2 matches the np/jax fp32 reference ---
__device__ __forceinline__ float sq_nofma(float v) {
  float r = v * v;
  asm volatile("" : "+v"(r));
  return r;
}

// One wave computes the ball-query index list (32 ints) for one query point.
// Writes first min(cnt,32) in-radius indices in increasing order, padded with
// first-hit (or 0 if none).
__device__ __forceinline__ void ball_query_wave(
    const float* __restrict__ xb,  // xyz for this batch: [N][3]
    float qx, float qy, float qz, int lane, int* out /* 32 ints */) {
  const float R2 = 0.01f;  // float32(0.1*0.1 in f64) == 0x3C23D70A
  int cnt = 0;
  int firstIdx = 0;
  for (int base = 0; base < NN; base += 256) {
    float px[4], py[4], pz[4];
#pragma unroll
    for (int j = 0; j < 4; ++j) {
      int n = base + j * 64 + lane;
      const float* p = xb + n * 3;
      px[j] = p[0];
      py[j] = p[1];
      pz[j] = p[2];
    }
#pragma unroll
    for (int j = 0; j < 4; ++j) {
      float dx = px[j] - qx, dy = py[j] - qy, dz = pz[j] - qz;
      float d2 = sq_nofma(dx) + sq_nofma(dy);
      asm volatile("" : "+v"(d2));
      d2 = d2 + sq_nofma(dz);
      bool m = d2 < R2;
      unsigned long long bal = __ballot(m);
      if (cnt == 0 && bal) firstIdx = base + j * 64 + __builtin_ctzll(bal);
      int pos = cnt + (int)__popcll(bal & ((1ull << lane) - 1ull));
      if (m && pos < NS) out[pos] = base + j * 64 + lane;
      cnt += (int)__popcll(bal);
    }
    if (cnt >= NS) break;  // wave-uniform early exit; later n are irrelevant
  }
  if (cnt < NS) {
    int pad = (cnt == 0) ? 0 : firstIdx;
    if (lane >= cnt && lane < NS) out[lane] = pad;
  }
}

// Kernel 1: ball query -> d_ws index table [B*S][32]
__global__ __launch_bounds__(256) void qg_ballq(
    const float* __restrict__ xyz, const float* __restrict__ nxyz,
    int* __restrict__ wsidx) {
  int q = (int)((blockIdx.x * blockDim.x + threadIdx.x) >> 6);
  int lane = (int)(threadIdx.x & 63);
  int b = q / SS;
  const float* xb = xyz + (size_t)b * NN * 3;
  float qx = nxyz[q * 3 + 0];
  float qy = nxyz[q * 3 + 1];
  float qz = nxyz[q * 3 + 2];
  ball_query_wave(xb, qx, qy, qz, lane, wsidx + (size_t)q * NS);
}

// Kernel 2: one thread per output element; coalesced writes, gather reads.
__global__ __launch_bounds__(256) void qg_gather(
    const float* __restrict__ xyz, const float* __restrict__ nxyz,
    const float* __restrict__ feat, const int* __restrict__ fps,
    const int* __restrict__ wsidx, float* __restrict__ out) {
  unsigned t = blockIdx.x * 256u + threadIdx.x;
  const unsigned TOT = (unsigned)BB * OC * SS * KK;
  if (t >= TOT) return;
  unsigned k = t % KK;
  unsigned r = t / KK;
  unsigned s = r % SS;
  r /= SS;
  unsigned c = r % OC;
  unsigned b = r / OC;
  unsigned q = b * SS + s;
  int n = (k == 0) ? fps[q] : wsidx[(size_t)q * NS + (k - 1)];
  float v;
  if (c < 6) {
    unsigned cc = (c < 3) ? c : c - 3;
    v = xyz[((size_t)b * NN + (unsigned)n) * 3 + cc];
    if (c >= 3) v -= nxyz[q * 3 + cc];
  } else {
    v = feat[((size_t)b * CC + (c - 6)) * NN + (unsigned)n];
  }
  out[t] = v;
}

// Fallback: fused single-kernel path (used only if ws_size is too small).
__global__ __launch_bounds__(256) void qg_fused(
    const float* __restrict__ xyz, const float* __restrict__ nxyz,
    const float* __restrict__ feat, const int* __restrict__ fps,
    float* __restrict__ out) {
  __shared__ int sidx[4][KK];
  int wv = (int)(threadIdx.x >> 6), lane = (int)(threadIdx.x & 63);
  int q = (int)blockIdx.x * 4 + wv;
  int b = q / SS, s = q % SS;
  const float* xb = xyz + (size_t)b * NN * 3;
  float qx = nxyz[q * 3 + 0];
  float qy = nxyz[q * 3 + 1];
  float qz = nxyz[q * 3 + 2];
  ball_query_wave(xb, qx, qy, qz, lane, &sidx[wv][1]);
  if (lane == 0) sidx[wv][0] = fps[q];
  __syncthreads();
  for (int f = lane; f < OC * KK; f += 64) {
    int c = f / KK, k = f - c * KK;
    int n = sidx[wv][k];
    float v;
    if (c < 6) {
      int cc = (c < 3) ? c : c - 3;
      v = xb[n * 3 + cc];
      if (c >= 3) v -= nxyz[q * 3 + cc];
    } else {
      v = feat[((size_t)b * CC + (c - 6)) * NN + n];
    }
    out[((size_t)((size_t)b * OC + c) * SS + s) * KK + k] = v;
  }
}

extern "C" void kernel_launch(void* const* d_in, const int* in_sizes, int n_in,
                              void* d_out, int out_size, void* d_ws, size_t ws_size,
                              hipStream_t stream) {
  const float* xyz  = (const float*)d_in[0];   // (B, N, 3)
  const float* nxyz = (const float*)d_in[1];   // (B, S, 3)
  const float* feat = (const float*)d_in[2];   // (B, C, N)
  const int*   fps  = (const int*)d_in[3];     // (B, S)
  float* out = (float*)d_out;                  // (B, 70, S, 33)

  const size_t need = (size_t)BB * SS * NS * sizeof(int);  // 1 MiB
  if (ws_size >= need) {
    int* wsidx = (int*)d_ws;
    qg_ballq<<<(BB * SS) / 4, 256, 0, stream>>>(xyz, nxyz, wsidx);
    unsigned tot = (unsigned)BB * OC * SS * KK;  // 18,923,520
    qg_gather<<<(tot + 255u) / 256u, 256, 0, stream>>>(xyz, nxyz, feat, fps,
                                                       wsidx, out);
  } else {
    qg_fused<<<(BB * SS) / 4, 256, 0, stream>>>(xyz, nxyz, feat, fps, out);
  }
}

// Round 2
// 77.350 us; speedup vs baseline: 1.7210x; 1.7210x over previous
//
#include <hip/hip_runtime.h>

#define BB 4
#define NN 16384
#define SS 2048
#define CC 64
#define NS 32
#define KK 33   // NS + 1 (fps_idx prepended)
#define OC 70   // 3 raw xyz + 3 centered xyz + 64 features
#define SCH 4   // s-chunk per gather block
#define GT 512  // gather block threads

// --- prevent fma contraction so d2 matches the np/jax fp32 reference ---
__device__ __forceinline__ float sq_nofma(float v) {
  float r = v * v;
  asm volatile("" : "+v"(r));
  return r;
}

// ---------------- legacy wave ball-query (fallback paths) ----------------
__device__ __forceinline__ void ball_query_wave(
    const float* __restrict__ xb, float qx, float qy, float qz, int lane,
    int* out) {
  const float R2 = 0.01f;
  int cnt = 0;
  int firstIdx = 0;
  for (int base = 0; base < NN; base += 256) {
    float px[4], py[4], pz[4];
#pragma unroll
    for (int j = 0; j < 4; ++j) {
      int n = base + j * 64 + lane;
      const float* p = xb + n * 3;
      px[j] = p[0]; py[j] = p[1]; pz[j] = p[2];
    }
#pragma unroll
    for (int j = 0; j < 4; ++j) {
      float dx = px[j] - qx, dy = py[j] - qy, dz = pz[j] - qz;
      float d2 = sq_nofma(dx) + sq_nofma(dy);
      asm volatile("" : "+v"(d2));
      d2 = d2 + sq_nofma(dz);
      bool m = d2 < R2;
      unsigned long long bal = __ballot(m);
      if (cnt == 0 && bal) firstIdx = base + j * 64 + __builtin_ctzll(bal);
      int pos = cnt + (int)__popcll(bal & ((1ull << lane) - 1ull));
      if (m && pos < NS) out[pos] = base + j * 64 + lane;
      cnt += (int)__popcll(bal);
    }
    if (cnt >= NS) break;
  }
  if (cnt < NS) {
    int pad = (cnt == 0) ? 0 : firstIdx;
    if (lane >= cnt && lane < NS) out[lane] = pad;
  }
}

// ---------------- Kernel 1: fused ball-query + feature transpose ----------
// Blocks with bid%3<2 do ball query (wave per query, float4 point loads);
// blocks with bid%3==2 transpose feat (B,C,N) -> featT (B,N,C).
__global__ __launch_bounds__(256) void qg_prep(
    const float* __restrict__ xyz, const float* __restrict__ nxyz,
    const float* __restrict__ feat, int* __restrict__ wsidx,
    float* __restrict__ featT) {
  __shared__ float tile[64][65];
  int bid = (int)blockIdx.x;
  int r3 = bid % 3;
  if (r3 < 2) {
    // ---- ball query ----
    int lane = (int)(threadIdx.x & 63);
    int q = ((bid / 3) * 2 + r3) * 4 + (int)(threadIdx.x >> 6);
    int b = q >> 11;  // / SS
    const float* xb = xyz + (size_t)b * NN * 3;
    float qx = nxyz[q * 3 + 0];
    float qy = nxyz[q * 3 + 1];
    float qz = nxyz[q * 3 + 2];
    int* out = wsidx + (size_t)q * NS;
    const float R2 = 0.01f;
    int cnt = 0, firstIdx = 0;
    unsigned long long lt = (1ull << lane) - 1ull;
    for (int base = 0; base < NN; base += 256) {
      const float4* p4 = (const float4*)(xb + (size_t)(base + lane * 4) * 3);
      float4 va = p4[0], vb = p4[1], vc = p4[2];
      float f[12] = {va.x, va.y, va.z, va.w, vb.x, vb.y, vb.z, vb.w,
                     vc.x, vc.y, vc.z, vc.w};
      unsigned mymask = 0;
      unsigned long long bal[4];
#pragma unroll
      for (int i = 0; i < 4; ++i) {
        float dx = f[3 * i] - qx, dy = f[3 * i + 1] - qy, dz = f[3 * i + 2] - qz;
        float d2 = sq_nofma(dx) + sq_nofma(dy);
        asm volatile("" : "+v"(d2));
        d2 = d2 + sq_nofma(dz);
        bool m = d2 < R2;
        bal[i] = __ballot(m);
        if (m) mymask |= 1u << i;
      }
      int basecnt = cnt + (int)(__popcll(bal[0] & lt) + __popcll(bal[1] & lt) +
                                __popcll(bal[2] & lt) + __popcll(bal[3] & lt));
      unsigned long long orb = bal[0] | bal[1] | bal[2] | bal[3];
      if (cnt == 0 && orb) {
        int L = __builtin_ctzll(orb);
        int ii = ((bal[0] >> L) & 1) ? 0
                 : ((bal[1] >> L) & 1) ? 1
                 : ((bal[2] >> L) & 1) ? 2 : 3;
        firstIdx = base + L * 4 + ii;
      }
      int off = 0;
#pragma unroll
      for (int i = 0; i < 4; ++i) {
        if (mymask & (1u << i)) {
          int pos = basecnt + off;
          if (pos < NS) out[pos] = base + lane * 4 + i;
          ++off;
        }
      }
      cnt += (int)(__popcll(bal[0]) + __popcll(bal[1]) + __popcll(bal[2]) +
                   __popcll(bal[3]));
      if (cnt >= NS) break;  // wave-uniform early exit
    }
    if (cnt < NS) {
      int pad = (cnt == 0) ? 0 : firstIdx;
      if (lane >= cnt && lane < NS) out[lane] = pad;
    }
  } else {
    // ---- feature transpose: 64c x 64n tile ----
    int tb = bid / 3;           // 0..1023
    int b = tb >> 8;            // / 256
    int n0 = (tb & 255) << 6;   // *64
    int tx = (int)(threadIdx.x & 63);
    int ty = (int)(threadIdx.x >> 6);  // 0..3
    const float* fb = feat + (size_t)b * CC * NN + n0;
#pragma unroll
    for (int r = 0; r < 16; ++r) {
      int c = r * 4 + ty;
      tile[c][tx] = fb[(size_t)c * NN + tx];
    }
    __syncthreads();
    float* ob = featT + ((size_t)b * NN + n0) * CC;
#pragma unroll
    for (int r = 0; r < 16; ++r) {
      int n = r * 4 + ty;
      ob[(size_t)n * CC + tx] = tile[tx][n];
    }
  }
}

// ---------------- Kernel 2: gather via featT + LDS retile ----------------
// Block = (b, 4 consecutive s). Reads featT rows 256B-contiguous, retiles in
// LDS to [c][s4*33+k], writes out in 528B contiguous runs per channel.
__global__ __launch_bounds__(GT) void qg_gather2(
    const float* __restrict__ xyz, const float* __restrict__ nxyz,
    const float* __restrict__ featT, const int* __restrict__ fps,
    const int* __restrict__ wsidx, float* __restrict__ out) {
  __shared__ float sf[CC][SCH * KK + 1];  // [64][133]
  __shared__ int sidx[SCH * KK];          // 132
  const int tid = (int)threadIdx.x;
  const int blk = (int)blockIdx.x;  // 0..2047
  const int b = blk >> 9;           // / (SS/SCH)
  const int s0 = (blk & 511) * SCH;
  const size_t cstr = (size_t)SS * KK;

  if (tid < SCH * KK) {
    int s4 = tid / KK, k = tid - s4 * KK;
    int q = b * SS + s0 + s4;
    sidx[tid] = (k == 0) ? fps[q] : wsidx[(size_t)q * NS + (k - 1)];
  }
  __syncthreads();

  // gather features -> LDS
  const float4* fT4 = (const float4*)(featT + (size_t)b * NN * CC);
  int e = tid & 15;
  for (int pp = tid >> 4; pp < SCH * KK; pp += GT / 16) {
    int n = sidx[pp];
    float4 v = fT4[(size_t)n * (CC / 4) + e];
    sf[4 * e + 0][pp] = v.x;
    sf[4 * e + 1][pp] = v.y;
    sf[4 * e + 2][pp] = v.z;
    sf[4 * e + 3][pp] = v.w;
  }

  // xyz channels (0..5), direct coalesced writes
  if (tid < SCH * KK) {
    int s4 = tid / KK;
    int n = sidx[tid];
    const float* p = xyz + ((size_t)b * NN + n) * 3;
    float x = p[0], y = p[1], z = p[2];
    int q = b * SS + s0 + s4;
    float cx = nxyz[q * 3 + 0], cy = nxyz[q * 3 + 1], cz = nxyz[q * 3 + 2];
    size_t obase = ((size_t)(b * OC) * SS + s0) * KK + tid;
    out[obase + 0 * cstr] = x;
    out[obase + 1 * cstr] = y;
    out[obase + 2 * cstr] = z;
    out[obase + 3 * cstr] = x - cx;
    out[obase + 4 * cstr] = y - cy;
    out[obase + 5 * cstr] = z - cz;
  }
  __syncthreads();

  // write features from LDS, linear per channel row
  size_t fbase = ((size_t)(b * OC + 6) * SS + s0) * KK;
  for (int idx = tid; idx < CC * SCH * KK; idx += GT) {
    int c = idx / (SCH * KK);
    int j = idx - c * (SCH * KK);
    out[fbase + (size_t)c * cstr + j] = sf[c][j];
  }
}

// ---------------- legacy fallback kernels ----------------
__global__ __launch_bounds__(256) void qg_ballq(
    const float* __restrict__ xyz, const float* __restrict__ nxyz,
    int* __restrict__ wsidx) {
  int q = (int)((blockIdx.x * blockDim.x + threadIdx.x) >> 6);
  int lane = (int)(threadIdx.x & 63);
  int b = q / SS;
  const float* xb = xyz + (size_t)b * NN * 3;
  ball_query_wave(xb, nxyz[q * 3], nxyz[q * 3 + 1], nxyz[q * 3 + 2], lane,
                  wsidx + (size_t)q * NS);
}

__global__ __launch_bounds__(256) void qg_gather(
    const float* __restrict__ xyz, const float* __restrict__ nxyz,
    const float* __restrict__ feat, const int* __restrict__ fps,
    const int* __restrict__ wsidx, float* __restrict__ out) {
  unsigned t = blockIdx.x * 256u + threadIdx.x;
  const unsigned TOT = (unsigned)BB * OC * SS * KK;
  if (t >= TOT) return;
  unsigned k = t % KK;
  unsigned r = t / KK;
  unsigned s = r % SS;
  r /= SS;
  unsigned c = r % OC;
  unsigned b = r / OC;
  unsigned q = b * SS + s;
  int n = (k == 0) ? fps[q] : wsidx[(size_t)q * NS + (k - 1)];
  float v;
  if (c < 6) {
    unsigned cc = (c < 3) ? c : c - 3;
    v = xyz[((size_t)b * NN + (unsigned)n) * 3 + cc];
    if (c >= 3) v -= nxyz[q * 3 + cc];
  } else {
    v = feat[((size_t)b * CC + (c - 6)) * NN + (unsigned)n];
  }
  out[t] = v;
}

__global__ __launch_bounds__(256) void qg_fused(
    const float* __restrict__ xyz, const float* __restrict__ nxyz,
    const float* __restrict__ feat, const int* __restrict__ fps,
    float* __restrict__ out) {
  __shared__ int sidx[4][KK];
  int wv = (int)(threadIdx.x >> 6), lane = (int)(threadIdx.x & 63);
  int q = (int)blockIdx.x * 4 + wv;
  int b = q / SS, s = q % SS;
  const float* xb = xyz + (size_t)b * NN * 3;
  ball_query_wave(xb, nxyz[q * 3], nxyz[q * 3 + 1], nxyz[q * 3 + 2], lane,
                  &sidx[wv][1]);
  if (lane == 0) sidx[wv][0] = fps[q];
  __syncthreads();
  for (int f = lane; f < OC * KK; f += 64) {
    int c = f / KK, k = f - c * KK;
    int n = sidx[wv][k];
    float v;
    if (c < 6) {
      int cc = (c < 3) ? c : c - 3;
      v = xb[n * 3 + cc];
      if (c >= 3) v -= nxyz[q * 3 + cc];
    } else {
      v = feat[((size_t)b * CC + (c - 6)) * NN + n];
    }
    out[((size_t)((size_t)b * OC + c) * SS + s) * KK + k] = v;
  }
}

extern "C" void kernel_launch(void* const* d_in, const int* in_sizes, int n_in,
                              void* d_out, int out_size, void* d_ws, size_t ws_size,
                              hipStream_t stream) {
  const float* xyz  = (const float*)d_in[0];   // (B, N, 3)
  const float* nxyz = (const float*)d_in[1];   // (B, S, 3)
  const float* feat = (const float*)d_in[2];   // (B, C, N)
  const int*   fps  = (const int*)d_in[3];     // (B, S)
  float* out = (float*)d_out;                  // (B, 70, S, 33)

  const size_t idx_bytes = (size_t)BB * SS * NS * sizeof(int);        // 1 MiB
  const size_t featT_bytes = (size_t)BB * NN * CC * sizeof(float);    // 16.8 MB
  if (ws_size >= idx_bytes + featT_bytes) {
    int* wsidx = (int*)d_ws;
    float* featT = (float*)((char*)d_ws + idx_bytes);
    qg_prep<<<3072, 256, 0, stream>>>(xyz, nxyz, feat, wsidx, featT);
    qg_gather2<<<BB * (SS / SCH), GT, 0, stream>>>(xyz, nxyz, featT, fps,
                                                   wsidx, out);
  } else if (ws_size >= idx_bytes) {
    int* wsidx = (int*)d_ws;
    qg_ballq<<<(BB * SS) / 4, 256, 0, stream>>>(xyz, nxyz, wsidx);
    unsigned tot = (unsigned)BB * OC * SS * KK;
    qg_gather<<<(tot + 255u) / 256u, 256, 0, stream>>>(xyz, nxyz, feat, fps,
                                                       wsidx, out);
  } else {
    qg_fused<<<(BB * SS) / 4, 256, 0, stream>>>(xyz, nxyz, feat, fps, out);
  }
}

// Round 3
// 72.669 us; speedup vs baseline: 1.8319x; 1.0644x over previous
//
#include <hip/hip_runtime.h>

#define BB 4
#define NN 16384
#define SS 2048
#define CC 64
#define NS 32
#define KK 33   // NS + 1 (fps_idx prepended)
#define OC 70   // 3 raw xyz + 3 centered xyz + 64 features
#define SCH 4   // s-chunk per gather block
#define GT 512  // gather block threads
#define NC 10
#define NCELL 1000
#define HCAP 224         // per-wave hit buffer cap (avg hits ~68)
#define RPAD 0.100001f   // cell-range pad (covers fp rounding of d2 test)

// --- prevent fma contraction so d2 matches the np/jax fp32 reference ---
__device__ __forceinline__ float sq_nofma(float v) {
  float r = v * v;
  asm volatile("" : "+v"(r));
  return r;
}

__device__ __forceinline__ int cell1(float x) {
  int c = (int)(x * 10.0f);
  return c < 0 ? 0 : (c > 9 ? 9 : c);
}
__device__ __forceinline__ int cell3(float x, float y, float z) {
  return (cell1(z) * NC + cell1(y)) * NC + cell1(x);
}

// ---------------- legacy wave ball-query (fallback + overflow path) -------
__device__ __forceinline__ void ball_query_wave(
    const float* __restrict__ xb, float qx, float qy, float qz, int lane,
    int* out) {
  const float R2 = 0.01f;
  int cnt = 0;
  int firstIdx = 0;
  for (int base = 0; base < NN; base += 256) {
    float px[4], py[4], pz[4];
#pragma unroll
    for (int j = 0; j < 4; ++j) {
      int n = base + j * 64 + lane;
      const float* p = xb + n * 3;
      px[j] = p[0]; py[j] = p[1]; pz[j] = p[2];
    }
#pragma unroll
    for (int j = 0; j < 4; ++j) {
      float dx = px[j] - qx, dy = py[j] - qy, dz = pz[j] - qz;
      float d2 = sq_nofma(dx) + sq_nofma(dy);
      asm volatile("" : "+v"(d2));
      d2 = d2 + sq_nofma(dz);
      bool m = d2 < R2;
      unsigned long long bal = __ballot(m);
      if (cnt == 0 && bal) firstIdx = base + j * 64 + __builtin_ctzll(bal);
      int pos = cnt + (int)__popcll(bal & ((1ull << lane) - 1ull));
      if (m && pos < NS) out[pos] = base + j * 64 + lane;
      cnt += (int)__popcll(bal);
    }
    if (cnt >= NS) break;
  }
  if (cnt < NS) {
    int pad = (cnt == 0) ? 0 : firstIdx;
    if (lane >= cnt && lane < NS) out[lane] = pad;
  }
}

// ---------------- K1: grid build (4 blocks) + feature transpose -----------
__global__ __launch_bounds__(256) void qg_build_tr(
    const float* __restrict__ xyz, const float* __restrict__ feat,
    int* __restrict__ off, int* __restrict__ woff, float* __restrict__ featT) {
  __shared__ float tile[64][65];
  __shared__ int h[1024];
  __shared__ int sc[256];
  const int bid = (int)blockIdx.x;
  const int tid = (int)threadIdx.x;
  if (bid < BB) {
    // ---- build histogram + exclusive scan for batch `bid` ----
    const int b = bid;
    const float* xb = xyz + (size_t)b * NN * 3;
    for (int c = tid; c < 1024; c += 256) h[c] = 0;
    __syncthreads();
    for (int i = tid; i < NN; i += 256) {
      const float* p = xb + 3 * i;
      atomicAdd(&h[cell3(p[0], p[1], p[2])], 1);
    }
    __syncthreads();
    int base = tid * 4;
    int l0 = h[base], l1 = h[base + 1], l2 = h[base + 2], l3 = h[base + 3];
    int s1 = l0, s2 = l0 + l1, s3 = l0 + l1 + l2, tot = s3 + l3;
    sc[tid] = tot;
    __syncthreads();
    for (int d = 1; d < 256; d <<= 1) {
      int v = (tid >= d) ? sc[tid - d] : 0;
      __syncthreads();
      sc[tid] += v;
      __syncthreads();
    }
    int ex = sc[tid] - tot;
    int* offb = off + b * (NCELL + 1);
    int* woffb = woff + b * NCELL;
    if (base + 0 < NCELL) { offb[base + 0] = ex;      woffb[base + 0] = ex; }
    if (base + 1 < NCELL) { offb[base + 1] = ex + s1; woffb[base + 1] = ex + s1; }
    if (base + 2 < NCELL) { offb[base + 2] = ex + s2; woffb[base + 2] = ex + s2; }
    if (base + 3 < NCELL) { offb[base + 3] = ex + s3; woffb[base + 3] = ex + s3; }
    if (tid == 0) offb[NCELL] = NN;
  } else {
    // ---- feature transpose: 64c x 64n tile ----
    int tb = bid - BB;          // 0..1023
    int b = tb >> 8;
    int n0 = (tb & 255) << 6;
    int tx = tid & 63;
    int ty = tid >> 6;  // 0..3
    const float* fb = feat + (size_t)b * CC * NN + n0;
#pragma unroll
    for (int r = 0; r < 16; ++r) {
      int c = r * 4 + ty;
      tile[c][tx] = fb[(size_t)c * NN + tx];
    }
    __syncthreads();
    float* ob = featT + ((size_t)b * NN + n0) * CC;
#pragma unroll
    for (int r = 0; r < 16; ++r) {
      int n = r * 4 + ty;
      ob[(size_t)n * CC + tx] = tile[tx][n];
    }
  }
}

// ---------------- K2: counting-sort scatter into cell order ---------------
__global__ __launch_bounds__(256) void qg_scatter(
    const float* __restrict__ xyz, int* __restrict__ woff,
    float4* __restrict__ pts) {
  int i = (int)(blockIdx.x * 256u + threadIdx.x);  // 0..65535
  int b = i >> 14, n = i & (NN - 1);
  const float* p = xyz + ((size_t)b * NN + n) * 3;
  float x = p[0], y = p[1], z = p[2];
  int cell = cell3(x, y, z);
  int pos = atomicAdd(&woff[b * NCELL + cell], 1);
  pts[(b << 14) + pos] = make_float4(x, y, z, __int_as_float(n));
}

// ---------------- K3: grid ball query (one wave per query) ----------------
__global__ __launch_bounds__(256) void qg_query(
    const float* __restrict__ xyz, const float* __restrict__ nxyz,
    const float4* __restrict__ pts, const int* __restrict__ off,
    int* __restrict__ wsidx) {
  __shared__ int hitbuf[4][HCAP];
  const int tid = (int)threadIdx.x;
  const int lane = tid & 63;
  const int wv = tid >> 6;
  const int q = (int)blockIdx.x * 4 + wv;
  const int b = q >> 11;
  const float R2 = 0.01f;
  float qx = nxyz[q * 3 + 0];
  float qy = nxyz[q * 3 + 1];
  float qz = nxyz[q * 3 + 2];
  int* outp = wsidx + (size_t)q * NS;
  int* hb = hitbuf[wv];

  int lox = max(0, (int)floorf((qx - RPAD) * 10.f));
  int hix = min(9, (int)floorf((qx + RPAD) * 10.f));
  int loy = max(0, (int)floorf((qy - RPAD) * 10.f));
  int hiy = min(9, (int)floorf((qy + RPAD) * 10.f));
  int loz = max(0, (int)floorf((qz - RPAD) * 10.f));
  int hiz = min(9, (int)floorf((qz + RPAD) * 10.f));

  const int* offb = off + b * (NCELL + 1);
  const float4* pb = pts + ((size_t)b << 14);
  const unsigned long long lt = (1ull << lane) - 1ull;
  int hcnt = 0;
  bool ovf = false;

  for (int cz = loz; cz <= hiz && !ovf; ++cz) {
    for (int cy = loy; cy <= hiy && !ovf; ++cy) {
      int row = (cz * NC + cy) * NC;
      int start = offb[row + lox];
      int end = offb[row + hix + 1];
      for (int p0 = start; p0 < end; p0 += 64) {
        int ii = p0 + lane;
        bool valid = ii < end;
        float4 v = make_float4(1e30f, 1e30f, 1e30f, 0.f);
        if (valid) v = pb[ii];
        float dx = v.x - qx, dy = v.y - qy, dz = v.z - qz;
        float d2 = sq_nofma(dx) + sq_nofma(dy);
        asm volatile("" : "+v"(d2));
        d2 = d2 + sq_nofma(dz);
        bool m = valid && (d2 < R2);
        unsigned long long bal = __ballot(m);
        int inc = (int)__popcll(bal);
        if (hcnt + inc > HCAP) { ovf = true; break; }
        if (m) hb[hcnt + (int)__popcll(bal & lt)] = __float_as_int(v.w);
        hcnt += inc;
      }
    }
  }

  if (ovf) {
    // extremely rare safety net: exact legacy linear scan
    ball_query_wave(xyz + (size_t)b * NN * 3, qx, qy, qz, lane, outp);
    return;
  }

  asm volatile("s_waitcnt lgkmcnt(0)" ::: "memory");  // hb visible wave-wide

  const int M = hcnt;
  int minv = 0x7fffffff;
  for (int i = lane; i < M; i += 64) {
    int hh = hb[i];
    minv = min(minv, hh);
    int rank = 0;
    for (int j = 0; j < M; ++j) rank += (hb[j] < hh) ? 1 : 0;
    if (rank < NS) outp[rank] = hh;
  }
  if (M < NS) {
#pragma unroll
    for (int d = 1; d < 64; d <<= 1) minv = min(minv, __shfl_xor(minv, d, 64));
    int pad = (M == 0) ? 0 : minv;
    if (lane >= M && lane < NS) outp[lane] = pad;
  }
}

// ---------------- K4: gather via featT + LDS retile -----------------------
__global__ __launch_bounds__(GT) void qg_gather2(
    const float* __restrict__ xyz, const float* __restrict__ nxyz,
    const float* __restrict__ featT, const int* __restrict__ fps,
    const int* __restrict__ wsidx, float* __restrict__ out) {
  __shared__ float sf[CC][SCH * KK + 1];  // [64][133]
  __shared__ int sidx[SCH * KK];          // 132
  const int tid = (int)threadIdx.x;
  const int blk = (int)blockIdx.x;  // 0..2047
  const int b = blk >> 9;
  const int s0 = (blk & 511) * SCH;
  const size_t cstr = (size_t)SS * KK;

  if (tid < SCH * KK) {
    int s4 = tid / KK, k = tid - s4 * KK;
    int q = b * SS + s0 + s4;
    sidx[tid] = (k == 0) ? fps[q] : wsidx[(size_t)q * NS + (k - 1)];
  }
  __syncthreads();

  const float4* fT4 = (const float4*)(featT + (size_t)b * NN * CC);
  int e = tid & 15;
  for (int pp = tid >> 4; pp < SCH * KK; pp += GT / 16) {
    int n = sidx[pp];
    float4 v = fT4[(size_t)n * (CC / 4) + e];
    sf[4 * e + 0][pp] = v.x;
    sf[4 * e + 1][pp] = v.y;
    sf[4 * e + 2][pp] = v.z;
    sf[4 * e + 3][pp] = v.w;
  }

  if (tid < SCH * KK) {
    int s4 = tid / KK;
    int n = sidx[tid];
    const float* p = xyz + ((size_t)b * NN + n) * 3;
    float x = p[0], y = p[1], z = p[2];
    int q = b * SS + s0 + s4;
    float cx = nxyz[q * 3 + 0], cy = nxyz[q * 3 + 1], cz = nxyz[q * 3 + 2];
    size_t obase = ((size_t)(b * OC) * SS + s0) * KK + tid;
    out[obase + 0 * cstr] = x;
    out[obase + 1 * cstr] = y;
    out[obase + 2 * cstr] = z;
    out[obase + 3 * cstr] = x - cx;
    out[obase + 4 * cstr] = y - cy;
    out[obase + 5 * cstr] = z - cz;
  }
  __syncthreads();

  size_t fbase = ((size_t)(b * OC + 6) * SS + s0) * KK;
  for (int idx = tid; idx < CC * SCH * KK; idx += GT) {
    int c = idx / (SCH * KK);
    int j = idx - c * (SCH * KK);
    out[fbase + (size_t)c * cstr + j] = sf[c][j];
  }
}

// ---------------- legacy fallback kernels (small-ws paths) ----------------
__global__ __launch_bounds__(256) void qg_prep(
    const float* __restrict__ xyz, const float* __restrict__ nxyz,
    const float* __restrict__ feat, int* __restrict__ wsidx,
    float* __restrict__ featT) {
  __shared__ float tile[64][65];
  int bid = (int)blockIdx.x;
  int r3 = bid % 3;
  if (r3 < 2) {
    int lane = (int)(threadIdx.x & 63);
    int q = ((bid / 3) * 2 + r3) * 4 + (int)(threadIdx.x >> 6);
    int b = q >> 11;
    const float* xb = xyz + (size_t)b * NN * 3;
    ball_query_wave(xb, nxyz[q * 3], nxyz[q * 3 + 1], nxyz[q * 3 + 2], lane,
                    wsidx + (size_t)q * NS);
  } else {
    int tb = bid / 3;
    int b = tb >> 8;
    int n0 = (tb & 255) << 6;
    int tx = (int)(threadIdx.x & 63);
    int ty = (int)(threadIdx.x >> 6);
    const float* fb = feat + (size_t)b * CC * NN + n0;
#pragma unroll
    for (int r = 0; r < 16; ++r) {
      int c = r * 4 + ty;
      tile[c][tx] = fb[(size_t)c * NN + tx];
    }
    __syncthreads();
    float* ob = featT + ((size_t)b * NN + n0) * CC;
#pragma unroll
    for (int r = 0; r < 16; ++r) {
      int n = r * 4 + ty;
      ob[(size_t)n * CC + tx] = tile[tx][n];
    }
  }
}

__global__ __launch_bounds__(256) void qg_ballq(
    const float* __restrict__ xyz, const float* __restrict__ nxyz,
    int* __restrict__ wsidx) {
  int q = (int)((blockIdx.x * blockDim.x + threadIdx.x) >> 6);
  int lane = (int)(threadIdx.x & 63);
  int b = q / SS;
  const float* xb = xyz + (size_t)b * NN * 3;
  ball_query_wave(xb, nxyz[q * 3], nxyz[q * 3 + 1], nxyz[q * 3 + 2], lane,
                  wsidx + (size_t)q * NS);
}

__global__ __launch_bounds__(256) void qg_gather(
    const float* __restrict__ xyz, const float* __restrict__ nxyz,
    const float* __restrict__ feat, const int* __restrict__ fps,
    const int* __restrict__ wsidx, float* __restrict__ out) {
  unsigned t = blockIdx.x * 256u + threadIdx.x;
  const unsigned TOT = (unsigned)BB * OC * SS * KK;
  if (t >= TOT) return;
  unsigned k = t % KK;
  unsigned r = t / KK;
  unsigned s = r % SS;
  r /= SS;
  unsigned c = r % OC;
  unsigned b = r / OC;
  unsigned q = b * SS + s;
  int n = (k == 0) ? fps[q] : wsidx[(size_t)q * NS + (k - 1)];
  float v;
  if (c < 6) {
    unsigned cc = (c < 3) ? c : c - 3;
    v = xyz[((size_t)b * NN + (unsigned)n) * 3 + cc];
    if (c >= 3) v -= nxyz[q * 3 + cc];
  } else {
    v = feat[((size_t)b * CC + (c - 6)) * NN + (unsigned)n];
  }
  out[t] = v;
}

__global__ __launch_bounds__(256) void qg_fused(
    const float* __restrict__ xyz, const float* __restrict__ nxyz,
    const float* __restrict__ feat, const int* __restrict__ fps,
    float* __restrict__ out) {
  __shared__ int sidx[4][KK];
  int wv = (int)(threadIdx.x >> 6), lane = (int)(threadIdx.x & 63);
  int q = (int)blockIdx.x * 4 + wv;
  int b = q / SS, s = q % SS;
  const float* xb = xyz + (size_t)b * NN * 3;
  ball_query_wave(xb, nxyz[q * 3], nxyz[q * 3 + 1], nxyz[q * 3 + 2], lane,
                  &sidx[wv][1]);
  if (lane == 0) sidx[wv][0] = fps[q];
  __syncthreads();
  for (int f = lane; f < OC * KK; f += 64) {
    int c = f / KK, k = f - c * KK;
    int n = sidx[wv][k];
    float v;
    if (c < 6) {
      int cc = (c < 3) ? c : c - 3;
      v = xb[n * 3 + cc];
      if (c >= 3) v -= nxyz[q * 3 + cc];
    } else {
      v = feat[((size_t)b * CC + (c - 6)) * NN + n];
    }
    out[((size_t)((size_t)b * OC + c) * SS + s) * KK + k] = v;
  }
}

extern "C" void kernel_launch(void* const* d_in, const int* in_sizes, int n_in,
                              void* d_out, int out_size, void* d_ws, size_t ws_size,
                              hipStream_t stream) {
  const float* xyz  = (const float*)d_in[0];   // (B, N, 3)
  const float* nxyz = (const float*)d_in[1];   // (B, S, 3)
  const float* feat = (const float*)d_in[2];   // (B, C, N)
  const int*   fps  = (const int*)d_in[3];     // (B, S)
  float* out = (float*)d_out;                  // (B, 70, S, 33)

  const size_t idx_b   = (size_t)BB * SS * NS * sizeof(int);     // 1 MiB
  const size_t pts_b   = (size_t)BB * NN * sizeof(float4);       // 1 MiB
  const size_t off_b   = 16384;                                  // 4*1001*4 padded
  const size_t woff_b  = 16384;
  const size_t featT_b = (size_t)BB * NN * CC * sizeof(float);   // 16.8 MB
  const size_t grid_need = idx_b + pts_b + off_b + woff_b + featT_b;

  if (ws_size >= grid_need) {
    char* w = (char*)d_ws;
    int*    wsidx = (int*)w;                       w += idx_b;
    float4* pts   = (float4*)w;                    w += pts_b;
    int*    off   = (int*)w;                       w += off_b;
    int*    woff  = (int*)w;                       w += woff_b;
    float*  featT = (float*)w;
    qg_build_tr<<<BB + 1024, 256, 0, stream>>>(xyz, feat, off, woff, featT);
    qg_scatter<<<(BB * NN) / 256, 256, 0, stream>>>(xyz, woff, pts);
    qg_query<<<(BB * SS) / 4, 256, 0, stream>>>(xyz, nxyz, pts, off, wsidx);
    qg_gather2<<<BB * (SS / SCH), GT, 0, stream>>>(xyz, nxyz, featT, fps,
                                                   wsidx, out);
  } else if (ws_size >= idx_b + featT_b) {
    int* wsidx = (int*)d_ws;
    float* featT = (float*)((char*)d_ws + idx_b);
    qg_prep<<<3072, 256, 0, stream>>>(xyz, nxyz, feat, wsidx, featT);
    qg_gather2<<<BB * (SS / SCH), GT, 0, stream>>>(xyz, nxyz, featT, fps,
                                                   wsidx, out);
  } else if (ws_size >= idx_b) {
    int* wsidx = (int*)d_ws;
    qg_ballq<<<(BB * SS) / 4, 256, 0, stream>>>(xyz, nxyz, wsidx);
    unsigned tot = (unsigned)BB * OC * SS * KK;
    qg_gather<<<(tot + 255u) / 256u, 256, 0, stream>>>(xyz, nxyz, feat, fps,
                                                       wsidx, out);
  } else {
    qg_fused<<<(BB * SS) / 4, 256, 0, stream>>>(xyz, nxyz, feat, fps, out);
  }
}